// Round 13
// baseline (787.605 us; speedup 1.0000x reference)
//
#include <hip/hip_runtime.h>
#include <math.h>

#define B_   32
#define L_   1024
#define C_   32
#define D_   512
#define SEG_ 16
#define SX_  64
#define N_   1024   // B*C

typedef _Float16 f16x8 __attribute__((ext_vector_type(8)));
typedef _Float16 f16x4 __attribute__((ext_vector_type(4)));
typedef float    f32x4 __attribute__((ext_vector_type(4)));

__device__ __forceinline__ void stage16(const void* g, void* l) {
    __builtin_amdgcn_global_load_lds((const __attribute__((address_space(1))) void*)g,
                                     (__attribute__((address_space(3))) void*)l, 16, 0, 0);
}
// SC0 LDS-DMA: L2-served h-data path (works because h-tile traffic capacity-
// evicts L1 lines between uses). R8 lesson: NOT valid for tight-loop polling —
// the ONLY correct poll primitive is an AGENT-scope atomic load.
__device__ __forceinline__ void stage16l(const void* g, void* l) {
    __builtin_amdgcn_global_load_lds((const __attribute__((address_space(1))) void*)g,
                                     (__attribute__((address_space(3))) void*)l, 16, 0, 1);
}
__device__ __forceinline__ void store_v4_sc0(void* p, f16x8 v) {
    asm volatile("global_store_dwordx4 %0, %1, off sc0" :: "v"(p), "v"(v) : "memory");
}
__device__ __forceinline__ float fsig(float x) {
    return __builtin_amdgcn_rcpf(1.f + __expf(-x));
}
__device__ __forceinline__ float ftanh(float x) {   // 1 - 2/(e^2x+1), stable both tails
    return 1.f - 2.f * __builtin_amdgcn_rcpf(1.f + __expf(2.f * x));
}

// ---------------------------------------------------------------------------
// fused setup: [0,6144) pack_wih | [6144,12288) pack_whh5 | [12288,16384)
// pack_pe | [16384,16512) prep.
// ---------------------------------------------------------------------------
__global__ __launch_bounds__(256) void setup_kernel(
    const float* __restrict__ x, float* __restrict__ xs_seg, float* __restrict__ xt_seg,
    const float* __restrict__ Wih_s, const float* __restrict__ Wih_t,
    _Float16* __restrict__ wih_pk,
    const float* __restrict__ Whh_s, const float* __restrict__ Whh_t,
    _Float16* __restrict__ whh_pk5,
    const float* __restrict__ pos_s, const float* __restrict__ ch_s,
    const float* __restrict__ pos_t, const float* __restrict__ ch_t,
    _Float16* __restrict__ pe) {
    int bid = blockIdx.x, tid = threadIdx.x;
    if (bid < 6144) {
        // pack Wih -> [gru][kt 16][gc 1536][32 k] f16
        int e = bid * 256 + tid;
        int kk = e & 31;
        int t = e >> 5;
        int gc = t % 1536;
        int t2 = t / 1536;
        int kt = t2 & 15, gru = t2 >> 4;
        int member = gc / 192, r = gc % 192;
        int wn = r / 48, r2 = r % 48;
        int gate = r2 >> 4, jl = r2 & 15;
        int j = member * 64 + wn * 16 + jl;
        int k = kt * 32 + kk;
        const float* W = gru ? Wih_t : Wih_s;
        wih_pk[e] = (_Float16)W[(size_t)(gate * 512 + j) * 512 + k];
    } else if (bid < 12288) {
        // pack Whh pre-swizzled: [gru][m 8][kt 4][chunk 3072][8 f16]
        int e = (bid - 6144) * 256 + tid;
        int fi = e & 7;
        int t = e >> 3;
        int c = t % 3072;
        int t2 = t / 3072;
        int kt = t2 & 3;
        int t3 = t2 >> 2;
        int member = t3 & 7, gru = t3 >> 3;
        int gc = c >> 4, s = c & 15;
        int q = s ^ (gc & 15);
        int k = kt * 128 + q * 8 + fi;
        int wn = gc / 48, r2 = gc % 48;
        int gate = r2 >> 4, jl = r2 & 15;
        int j = member * 64 + wn * 16 + jl;
        const float* W = gru ? Whh_t : Whh_s;
        whh_pk5[e] = (_Float16)W[(size_t)(gate * 512 + j) * 512 + k];
    } else if (bid < 16384) {
        // pe[gru][n][512] f16
        int e = (bid - 12288) * 256 + tid;
        int k = e & 511;
        int n = (e >> 9) & 1023;
        int gru = e >> 19;
        int c = n & 31;
        const float* pos = gru ? pos_t : pos_s;
        const float* ch  = gru ? ch_t  : ch_s;
        float v = (k < 256) ? pos[k] : ch[c * 256 + (k - 256)];
        pe[e] = (_Float16)v;
    } else {
        // prep: moving mean window 25, edge replication
        int b2 = bid - 16384;
        int b = b2 >> 2;
        int t = ((b2 & 3) << 8) + tid;
        const float* xb    = x + (size_t)b * (L_ * C_);
        const float* xrow  = xb + (size_t)t * C_;
        const float* xlast = xb + (size_t)(L_ - 1) * C_;
        float diff[C_];
#pragma unroll
        for (int c = 0; c < C_; ++c) diff[c] = xrow[c] - xlast[c];
        float ps[C_ + 1];
        ps[0] = 0.f;
#pragma unroll
        for (int c = 0; c < C_; ++c) ps[c + 1] = ps[c] + diff[c];
        int s = t >> 4, q = t & 15;
#pragma unroll
        for (int c = 0; c < C_; ++c) {
            int lo = c - 12, hi = c + 12;
            float sum = ps[(hi < 31 ? hi : 31) + 1] - ps[lo > 0 ? lo : 0];
            if (lo < 0)  sum += (float)(-lo)     * diff[0];
            if (hi > 31) sum += (float)(hi - 31) * diff[31];
            float mean = sum * (1.0f / 25.0f);
            size_t idx = ((size_t)s * N_ + (size_t)(b * C_ + c)) * SEG_ + q;
            xt_seg[idx] = mean;
            xs_seg[idx] = diff[c] - mean;
        }
    }
}

// ---------------------------------------------------------------------------
// emb batch: emb_buf[sl][gru][n][512] f16 = relu(xseg @ W_emb^T + b_emb)
// ---------------------------------------------------------------------------
__global__ __launch_bounds__(256) void emb_kernel(
    const float* __restrict__ xs_seg, const float* __restrict__ xt_seg,
    const float* __restrict__ W_emb, const float* __restrict__ b_emb,
    _Float16* __restrict__ emb_buf, int s0) {
    int bid = blockIdx.x;
    int gru = bid >> 8, sl = (bid >> 4) & 15, nch = bid & 15;
    int step = s0 + sl, n0 = nch * 64;
    const float* xseg = gru ? xt_seg : xs_seg;
    __shared__ float xl[64 * 16];
    int tid = threadIdx.x;
    const float* src = xseg + ((size_t)step * N_ + n0) * SEG_;
    for (int i = tid; i < 1024; i += 256) xl[i] = src[i];

    int kg = tid & 127;
    int rh = tid >> 7;
    float w[4][16], bb[4];
#pragma unroll
    for (int i = 0; i < 4; ++i) {
        int k = kg * 4 + i;
        const float4* wr = (const float4*)(W_emb + (size_t)k * 16);
#pragma unroll
        for (int v = 0; v < 4; ++v) {
            float4 tt = wr[v];
            w[i][v * 4 + 0] = tt.x; w[i][v * 4 + 1] = tt.y;
            w[i][v * 4 + 2] = tt.z; w[i][v * 4 + 3] = tt.w;
        }
        bb[i] = b_emb[k];
    }
    __syncthreads();
    _Float16* dst = emb_buf + ((size_t)(sl * 2 + gru) * N_ + n0) * D_ + kg * 4;
    for (int r = 0; r < 32; ++r) {
        int row = rh * 32 + r;
        float a0 = bb[0], a1 = bb[1], a2 = bb[2], a3 = bb[3];
#pragma unroll
        for (int q = 0; q < 16; ++q) {
            float xv = xl[row * 16 + q];
            a0 = fmaf(xv, w[0][q], a0);
            a1 = fmaf(xv, w[1][q], a1);
            a2 = fmaf(xv, w[2][q], a2);
            a3 = fmaf(xv, w[3][q], a3);
        }
        f16x4 v;
        v[0] = (_Float16)(a0 > 0.f ? a0 : 0.f);
        v[1] = (_Float16)(a1 > 0.f ? a1 : 0.f);
        v[2] = (_Float16)(a2 > 0.f ? a2 : 0.f);
        v[3] = (_Float16)(a3 > 0.f ? a3 : 0.f);
        *(f16x4*)(dst + (size_t)row * D_) = v;
    }
}

// ---------------------------------------------------------------------------
// gi GEMM v6: v3 tile (128M x 192N, BK=32, Mt=x&7) + TRIPLE-BUFFERED staging
// with counted vmcnt: issue batch kt+1 into buf[(kt+1)%3], then wait ONLY for
// batch kt (vmcnt(3) for w<4 which issues 3 DMAs/kt, vmcnt(2) for w>=4),
// leaving kt+1 in flight across the barrier. Triple buffer makes the second
// per-kt barrier unnecessary (buf[(kt+1)%3] was last read at kt-2, ordered by
// the kt-1 barrier). One sync/kt; DMA RTT hidden. LDS 60KB, 2 blocks/CU.
// ---------------------------------------------------------------------------
__global__ __launch_bounds__(512, 2) void gi_gemm_kernel(
    const _Float16* __restrict__ emb, const _Float16* __restrict__ pe,
    const _Float16* __restrict__ wih_pack,
    _Float16* __restrict__ gi, _Float16* __restrict__ gi_pe, int mode) {
    __shared__ __align__(16) char smem[61440];  // 3x8K A + 3x12K B; epi: 2x26624
    char* bufA[3] = { smem, smem + 8192, smem + 16384 };
    char* bufB[3] = { smem + 24576, smem + 36864, smem + 49152 };
    int Mt = blockIdx.x & 7, Nt = blockIdx.x >> 3;   // Nt = member 0..7
    int sl = blockIdx.y, gru = blockIdx.z;
    int tid = threadIdx.x, w = tid >> 6, lane = tid & 63;
    int wm = w & 1, wn = w >> 1, ml = lane & 15, qq = lane >> 4;

    const char* Ab = mode ? (const char*)(pe  + (size_t)gru * N_ * D_)
                          : (const char*)(emb + (size_t)(sl * 2 + gru) * N_ * D_);
    const char* Bb = (const char*)wih_pack + (size_t)gru * 16 * 1536 * 64
                     + (size_t)Nt * 192 * 64;

    // A staging: 512 chunks (128 rows x 4 swizzled quads), 1/thread
    int rA = tid >> 2, kqA = (tid & 3) ^ ((rA >> 1) & 3);
    const char* gA = Ab + (size_t)(Mt * 128 + rA) * 1024 + kqA * 16;
    // B staging: 768 chunks (192 gc x 4 quads): call1 all, call2 tid<256
    int g1 = tid >> 2, kq1 = (tid & 3) ^ ((g1 >> 1) & 3);
    int c2 = 512 + tid, g2 = c2 >> 2, kq2 = (c2 & 3) ^ ((g2 >> 1) & 3);

    int offA[4], offB[3];
#pragma unroll
    for (int mf = 0; mf < 4; ++mf) {
        int row = wm * 64 + mf * 16 + ml;
        offA[mf] = (row * 4 + (qq ^ ((row >> 1) & 3))) * 16;
    }
#pragma unroll
    for (int g = 0; g < 3; ++g) {
        int gc = wn * 48 + g * 16 + ml;
        offB[g] = (gc * 4 + (qq ^ ((gc >> 1) & 3))) * 16;
    }

    f32x4 acc[4][3];
#pragma unroll
    for (int mf = 0; mf < 4; ++mf)
#pragma unroll
        for (int g = 0; g < 3; ++g) {
            f32x4 z = {0.f, 0.f, 0.f, 0.f};
            acc[mf][g] = z;
        }

    // prologue: issue batch 0
    {
        stage16(gA, bufA[0] + w * 1024);
        const char* Bkt = Bb;
        stage16(Bkt + g1 * 64 + kq1 * 16, bufB[0] + w * 1024);
        if (w < 4) stage16(Bkt + g2 * 64 + kq2 * 16, bufB[0] + 8192 + w * 1024);
    }

#pragma unroll
    for (int kt = 0; kt < 16; ++kt) {
        if (kt < 15) {
            int kn = kt + 1;
            stage16(gA + kn * 64, bufA[kn % 3] + w * 1024);
            const char* Bkt = Bb + (size_t)kn * (1536 * 64);
            stage16(Bkt + g1 * 64 + kq1 * 16, bufB[kn % 3] + w * 1024);
            if (w < 4) {
                stage16(Bkt + g2 * 64 + kq2 * 16, bufB[kn % 3] + 8192 + w * 1024);
                asm volatile("s_waitcnt vmcnt(3)" ::: "memory");   // batch kt done
            } else {
                asm volatile("s_waitcnt vmcnt(2)" ::: "memory");
            }
        } else {
            asm volatile("s_waitcnt vmcnt(0)" ::: "memory");
        }
        __syncthreads();
        const char* cA = bufA[kt % 3];
        const char* cB = bufB[kt % 3];
        f16x8 a[4];
#pragma unroll
        for (int mf = 0; mf < 4; ++mf) a[mf] = *(const f16x8*)(cA + offA[mf]);
#pragma unroll
        for (int g = 0; g < 3; ++g) {
            f16x8 b = *(const f16x8*)(cB + offB[g]);
#pragma unroll
            for (int mf = 0; mf < 4; ++mf)
                acc[mf][g] = __builtin_amdgcn_mfma_f32_16x16x32_f16(a[mf], b, acc[mf][g], 0, 0, 0);
        }
    }

    // ---- epilogue: LDS transpose into consumer thread-packed layout ----
    __syncthreads();
#pragma unroll
    for (int mf = 0; mf < 4; ++mf) {
        int wm_c = mf >> 1, rt = mf & 1;
        int tid_c = (wn * 2 + wm_c) * 64 + qq * 16 + ml;
        char* base = smem + wm * 26624 + tid_c * 52;
#pragma unroll
        for (int g = 0; g < 3; ++g)
#pragma unroll
            for (int reg = 0; reg < 4; ++reg) {
                int v = rt * 12 + reg * 3 + g;
                *(_Float16*)(base + v * 2) = (_Float16)acc[mf][g][reg];
            }
    }
    __syncthreads();
    _Float16* ob = mode ? gi_pe + (size_t)gru * 8 * 16 * 512 * 24
                        : gi    + (size_t)(sl * 2 + gru) * 8 * 16 * 512 * 24;
    char* obB = (char*)ob;
#pragma unroll
    for (int s = 0; s < 6; ++s) {
        int o = tid * 16 + s * 8192;           // 0..49135 logical (2 slabs x 24576)
        int mc = o / 24576;
        int o2 = o - mc * 24576;
        int tc = o2 / 48;
        int r  = o2 - tc * 48;                 // 0 / 16 / 32 (never straddles)
        const char* src = smem + mc * 26624 + tc * 52 + r;
        int4 val;
        val.x = *(const int*)(src);
        val.y = *(const int*)(src + 4);
        val.z = *(const int*)(src + 8);
        val.w = *(const int*)(src + 12);
        *(int4*)(obB + (size_t)(Nt * 16 + Mt * 2 + mc) * 24576 + o2) = val;
    }
}

// ---------------------------------------------------------------------------
// Persistent chain scan v13: R6/R12 body + per-wave flag publish. vmcnt is a
// WAVE-level counter, so each wave's lane0 AGENT-atomic-stores its own flag
// word right after its own drain — no block-wide drain sync, no tid0
// serialization. 64 flag words/chain (member*8+wave), each on a private
// 128B line (R5/R7 lesson: pad lines, read-only poll). Wave 0's 64 lanes
// poll all 64 via AGENT atomic loads (R4's proven primitive, widened); the
// poll covers own block's flags too (intra-block sync preserved).
// ---------------------------------------------------------------------------
__global__ __launch_bounds__(512) void gru_chain_kernel(
    const _Float16* __restrict__ whh_pk5,  // [gru][m8][kt4][3072][8]
    const _Float16* __restrict__ gi_base,  // [it][gru][m8][Mt16][512][24]
    const float* __restrict__ bih_s, const float* __restrict__ bhh_s,
    const float* __restrict__ bih_t, const float* __restrict__ bhh_t,
    _Float16* __restrict__ hbf0, _Float16* __restrict__ hbf1,
    unsigned* __restrict__ flags, int nsteps, int sbase) {
    __shared__ __align__(16) char sA[65536];   // h tile [row 64][64 chunks x 16B], XOR-16 swizzle
    __shared__ __align__(16) char sEx[49152];  // partial-sum exchange: 12 planes x [256][16B]
    int bid = blockIdx.x;
    int member = bid >> 5, chain = bid & 31;   // co-location: bid%8 == chain%8 -> same XCD
    int Mt = chain & 15, gru = chain >> 4;
    int tid = threadIdx.x, w = tid >> 6, lane = tid & 63;
    int ml = lane & 15, qq = lane >> 4;
    int km = w & 1, wn = w >> 1;   // km: K-half, wn: j sub-block

    const char* h0 = (const char*)hbf0 + ((size_t)gru * N_ + Mt * 64) * 1024;
    const char* h1 = (const char*)hbf1 + ((size_t)gru * N_ + Mt * 64) * 1024;

    // Whh fragments persistent in registers: bfr[g][ks] (96 VGPRs)
    f16x8 bfr[3][8];
    {
        const _Float16* Wb = whh_pk5 + (size_t)(gru * 8 + member) * 4 * 24576;
#pragma unroll
        for (int g = 0; g < 3; ++g) {
            int gc = wn * 48 + g * 16 + ml;
#pragma unroll
            for (int ks = 0; ks < 8; ++ks) {
                int kt = km * 2 + (ks >> 2);
                int q8 = ((ks & 3) * 4 + qq) ^ (gc & 15);
                bfr[g][ks] = *(const f16x8*)(Wb + (size_t)kt * 24576
                                             + (size_t)(gc * 16 + q8) * 8);
            }
        }
    }

    int cS0 = (lane & 48) | ((lane & 15) ^ (w & 15));
    int cS1 = (lane & 48) | ((lane & 15) ^ ((w + 8) & 15));

    int offR[4], cp[8];
#pragma unroll
    for (int rt = 0; rt < 4; ++rt) offR[rt] = (rt * 16 + ml) * 1024;
#pragma unroll
    for (int ks = 0; ks < 8; ++ks) {
        int c = km * 32 + ks * 4 + qq;
        cp[ks] = ((c & 48) | ((c & 15) ^ ml)) * 16;
    }

    const float* bi = gru ? bih_t : bih_s;
    const float* bh = gru ? bhh_t : bhh_s;
    int j = member * 64 + wn * 16 + ml;
    float bir = bi[j], biz = bi[D_ + j], bin = bi[2 * D_ + j];
    float bhr = bh[j], bhz = bh[D_ + j], bhn = bh[2 * D_ + j];
    float hp[2][4];
#pragma unroll
    for (int rtL = 0; rtL < 2; ++rtL)
#pragma unroll
        for (int reg = 0; reg < 4; ++reg) {
            int row = Mt * 64 + km * 32 + rtL * 16 + qq * 4 + reg;
            hp[rtL][reg] = (float)hbf0[((size_t)gru * N_ + row) * D_ + j];
        }

    unsigned* fbase = flags + (size_t)chain * 2048;  // 8KB/chain; word (m*8+wv)*32
    const _Float16* giTid0 = gi_base
        + (((size_t)gru * 8 + member) * 16 + Mt) * 512 * 24 + (size_t)tid * 24;
    size_t giStep = (size_t)2 * 8 * 16 * 512 * 24;

    int dir0 = sbase & 1;
    f16x8 gv0, gv1, gv2;
    {
        const _Float16* gp = giTid0;
        gv0 = *(const f16x8*)(gp);
        gv1 = *(const f16x8*)(gp + 8);
        gv2 = *(const f16x8*)(gp + 16);
        const char* hin = dir0 ? h1 : h0;
#pragma unroll
        for (int r = 0; r < 8; ++r) {
            int row = r * 8 + w;
            stage16l(hin + (size_t)row * 1024 + (size_t)((r & 1) ? cS1 : cS0) * 16,
                     sA + row * 1024);
        }
    }

    for (int it = 0; it < nsteps; ++it) {
        int gstep = sbase + it;
        _Float16* hout = (gstep & 1) ? hbf0 : hbf1;

        f32x4 acc[4][3];
#pragma unroll
        for (int rt = 0; rt < 4; ++rt)
#pragma unroll
            for (int g = 0; g < 3; ++g) {
                f32x4 z = {0.f, 0.f, 0.f, 0.f};
                acc[rt][g] = z;
            }

        asm volatile("s_waitcnt vmcnt(0)" ::: "memory");   // A (+prev gi) arrival
        __syncthreads();

        // issue next-step gi (ping-pong regs); the publish vmcnt(0) is its wait
        int itn = (it + 1 < nsteps) ? it + 1 : it;
        const _Float16* gpn = giTid0 + (size_t)itn * giStep;
        f16x8 ngv0 = *(const f16x8*)(gpn);
        f16x8 ngv1 = *(const f16x8*)(gpn + 8);
        f16x8 ngv2 = *(const f16x8*)(gpn + 16);
        __builtin_amdgcn_sched_barrier(0);

#pragma unroll
        for (int ks = 0; ks < 8; ++ks) {
            f16x8 a0 = *(const f16x8*)(sA + offR[0] + cp[ks]);
            f16x8 a1 = *(const f16x8*)(sA + offR[1] + cp[ks]);
            f16x8 a2 = *(const f16x8*)(sA + offR[2] + cp[ks]);
            f16x8 a3 = *(const f16x8*)(sA + offR[3] + cp[ks]);
#pragma unroll
            for (int g = 0; g < 3; ++g) {
                acc[0][g] = __builtin_amdgcn_mfma_f32_16x16x32_f16(a0, bfr[g][ks], acc[0][g], 0, 0, 0);
                acc[1][g] = __builtin_amdgcn_mfma_f32_16x16x32_f16(a1, bfr[g][ks], acc[1][g], 0, 0, 0);
                acc[2][g] = __builtin_amdgcn_mfma_f32_16x16x32_f16(a2, bfr[g][ks], acc[2][g], 0, 0, 0);
                acc[3][g] = __builtin_amdgcn_mfma_f32_16x16x32_f16(a3, bfr[g][ks], acc[3][g], 0, 0, 0);
            }
        }

        // K-half reduce: publish the row-half this side does NOT finish.
        char* exw = sEx + (size_t)(wn * 64 + lane) * 16;
        if (km == 0) {
#pragma unroll
            for (int g = 0; g < 3; ++g) {
                *(f32x4*)(exw + (size_t)(6 + g) * 4096) = acc[2][g];
                *(f32x4*)(exw + (size_t)(9 + g) * 4096) = acc[3][g];
            }
        } else {
#pragma unroll
            for (int g = 0; g < 3; ++g) {
                *(f32x4*)(exw + (size_t)(0 + g) * 4096) = acc[0][g];
                *(f32x4*)(exw + (size_t)(3 + g) * 4096) = acc[1][g];
            }
        }
        __syncthreads();
        f32x4 s0[3], s1[3];
        if (km == 0) {
#pragma unroll
            for (int g = 0; g < 3; ++g) {
                s0[g] = acc[0][g] + *(const f32x4*)(exw + (size_t)(0 + g) * 4096);
                s1[g] = acc[1][g] + *(const f32x4*)(exw + (size_t)(3 + g) * 4096);
            }
        } else {
#pragma unroll
            for (int g = 0; g < 3; ++g) {
                s0[g] = acc[2][g] + *(const f32x4*)(exw + (size_t)(6 + g) * 4096);
                s1[g] = acc[3][g] + *(const f32x4*)(exw + (size_t)(9 + g) * 4096);
            }
        }

        // epilogue: compute 8 h/thread into LDS h-tile (aliases sA; A reads
        // all completed before the exchange barrier)
        char* sH = sA;                 // [64 rows][stride 144]
        int colb = (wn * 16 + ml) * 2;
#pragma unroll
        for (int reg = 0; reg < 4; ++reg) {     // rtL = 0
            int v0 = reg * 3;
            float gr = (float)((v0 + 0) < 8 ? gv0[(v0 + 0) & 7]
                      : ((v0 + 0) < 16 ? gv1[(v0 + 0) & 7] : gv2[(v0 + 0) & 7]));
            float gz = (float)((v0 + 1) < 8 ? gv0[(v0 + 1) & 7]
                      : ((v0 + 1) < 16 ? gv1[(v0 + 1) & 7] : gv2[(v0 + 1) & 7]));
            float gn = (float)((v0 + 2) < 8 ? gv0[(v0 + 2) & 7]
                      : ((v0 + 2) < 16 ? gv1[(v0 + 2) & 7] : gv2[(v0 + 2) & 7]));
            float r = fsig(s0[0][reg] + gr + bir + bhr);
            float z = fsig(s0[1][reg] + gz + biz + bhz);
            float nn = ftanh(gn + bin + r * (s0[2][reg] + bhn));
            float hv = (1.f - z) * nn + z * hp[0][reg];
            hp[0][reg] = hv;
            int rl = km * 32 + qq * 4 + reg;
            *(_Float16*)(sH + rl * 144 + colb) = (_Float16)hv;
        }
#pragma unroll
        for (int reg = 0; reg < 4; ++reg) {     // rtL = 1
            int v0 = 12 + reg * 3;
            float gr = (float)((v0 + 0) < 8 ? gv0[(v0 + 0) & 7]
                      : ((v0 + 0) < 16 ? gv1[(v0 + 0) & 7] : gv2[(v0 + 0) & 7]));
            float gz = (float)((v0 + 1) < 8 ? gv0[(v0 + 1) & 7]
                      : ((v0 + 1) < 16 ? gv1[(v0 + 1) & 7] : gv2[(v0 + 1) & 7]));
            float gn = (float)((v0 + 2) < 8 ? gv0[(v0 + 2) & 7]
                      : ((v0 + 2) < 16 ? gv1[(v0 + 2) & 7] : gv2[(v0 + 2) & 7]));
            float r = fsig(s1[0][reg] + gr + bir + bhr);
            float z = fsig(s1[1][reg] + gz + biz + bhz);
            float nn = ftanh(gn + bin + r * (s1[2][reg] + bhn));
            float hv = (1.f - z) * nn + z * hp[1][reg];
            hp[1][reg] = hv;
            int rl = km * 32 + 16 + qq * 4 + reg;
            *(_Float16*)(sH + rl * 144 + colb) = (_Float16)hv;
        }
        __syncthreads();
        // coalesced h store: 16B/thread
        {
            int srow = tid >> 3, spart = tid & 7;
            f16x8 hv8 = *(const f16x8*)(sH + srow * 144 + spart * 16);
            _Float16* gdst = hout + ((size_t)gru * N_ + Mt * 64 + srow) * D_
                             + member * 64 + spart * 8;
            store_v4_sc0(gdst, hv8);
        }

        // per-wave publish: vmcnt is wave-level — this wave's h stores (and
        // its gi prefetch) are drained once the waitcnt clears.
        asm volatile("s_waitcnt vmcnt(0)" ::: "memory");
        if (lane == 0)
            __hip_atomic_store(fbase + (member * 8 + w) * 32, (unsigned)(gstep + 1),
                               __ATOMIC_RELAXED, __HIP_MEMORY_SCOPE_AGENT);

        if (it < nsteps - 1) {
            if (w == 0) {
                const unsigned* fp = fbase + (size_t)lane * 32;   // lane <-> m*8+wv
                unsigned tgt = (unsigned)(gstep + 1);
                int guard = 0;
                while (true) {
                    unsigned v = __hip_atomic_load(fp, __ATOMIC_RELAXED,
                                                   __HIP_MEMORY_SCOPE_AGENT);
                    if (__all(v >= tgt)) break;
                    __builtin_amdgcn_s_sleep(1);
                    if (++guard > (1 << 20)) break;   // bail: fail, don't hang
                }
            }
            __syncthreads();
            const char* hinN = ((gstep + 1) & 1) ? h1 : h0;
#pragma unroll
            for (int r = 0; r < 8; ++r) {
                int row = r * 8 + w;
                stage16l(hinN + (size_t)row * 1024 + (size_t)((r & 1) ? cS1 : cS0) * 16,
                         sA + row * 1024);
            }
        }
        gv0 = ngv0; gv1 = ngv1; gv2 = ngv2;
    }
}

// ---------------------------------------------------------------------------
__global__ __launch_bounds__(256) void head_kernel(
    const _Float16* __restrict__ hs2, const _Float16* __restrict__ ht2,
    const float* __restrict__ Wps, const float* __restrict__ bps,
    const float* __restrict__ Wpt, const float* __restrict__ bpt,
    const float* __restrict__ x, float* __restrict__ out) {
    int g = blockIdx.x * 256 + threadIdx.x;
    int n = g >> 4, p = g & 15;
    int b = n >> 5, c = n & 31;
    const _Float16* hs = hs2 + (size_t)n * D_;
    const _Float16* ht = ht2 + (size_t)n * D_;
    const float* ws = Wps + (size_t)p * D_;
    const float* wt = Wpt + (size_t)p * D_;
    float acc = bps[p] + bpt[p];
    for (int k = 0; k < D_; ++k)
        acc += (float)hs[k] * ws[k] + (float)ht[k] * wt[k];
    float last = x[((size_t)b * L_ + (L_ - 1)) * C_ + c];
    out[((size_t)b * SEG_ + p) * C_ + c] = acc + last;
}

// ---------------------------------------------------------------------------
extern "C" void kernel_launch(void* const* d_in, const int* in_sizes, int n_in,
                              void* d_out, int out_size, void* d_ws, size_t ws_size,
                              hipStream_t stream) {
    const float* x     = (const float*)d_in[0];
    const float* W_emb = (const float*)d_in[1];
    const float* b_emb = (const float*)d_in[2];
    const float* Wih_s = (const float*)d_in[3];
    const float* Whh_s = (const float*)d_in[4];
    const float* bih_s = (const float*)d_in[5];
    const float* bhh_s = (const float*)d_in[6];
    const float* Wih_t = (const float*)d_in[7];
    const float* Whh_t = (const float*)d_in[8];
    const float* bih_t = (const float*)d_in[9];
    const float* bhh_t = (const float*)d_in[10];
    const float* pos_s = (const float*)d_in[11];
    const float* ch_s  = (const float*)d_in[12];
    const float* pos_t = (const float*)d_in[13];
    const float* ch_t  = (const float*)d_in[14];
    const float* Wps   = (const float*)d_in[15];
    const float* bps   = (const float*)d_in[16];
    const float* Wpt   = (const float*)d_in[17];
    const float* bpt   = (const float*)d_in[18];
    float* out = (float*)d_out;

    const size_t SZ_XS    = (size_t)SX_ * N_ * SEG_ * 4;            // 4 MB
    const size_t SZ_EMB   = (size_t)16 * 2 * N_ * D_ * 2;           // 32 MB
    const size_t SZ_GIB   = (size_t)16 * 2 * 8 * 16 * 512 * 24 * 2; // ~100.7 MB / batch
    const size_t SZ_GIPE  = (size_t)2 * 8 * 16 * 512 * 24 * 2;
    const size_t SZ_PE    = (size_t)2 * N_ * D_ * 2;
    const size_t SZ_WIH   = (size_t)2 * 16 * 1536 * 32 * 2;
    const size_t SZ_WHH   = (size_t)2 * 8 * 4 * 3072 * 8 * 2;
    const size_t SZ_H     = (size_t)2 * N_ * D_ * 2;
    const size_t SZ_FLAGS = (size_t)32 * 2048 * 4;                  // 256 KB
    const size_t fixed = 2 * SZ_XS + SZ_EMB + SZ_GIPE + SZ_PE + SZ_WIH + SZ_WHH
                         + 2 * SZ_H + SZ_FLAGS;
    // 2-batch tier (proven R12): two long chains; gi_pe sits contiguously
    // after gi_buf, so slab 32 of gi_buf IS gi_pe -> decoder folds into
    // chain 2 (33 steps).
    const bool big2 = ws_size >= fixed + 2 * SZ_GIB;
    const size_t gi_bytes = big2 ? 2 * SZ_GIB : SZ_GIB;

    char* p = (char*)d_ws;
    float* xs_seg = (float*)p;          p += SZ_XS;
    float* xt_seg = (float*)p;          p += SZ_XS;
    _Float16* emb_buf = (_Float16*)p;   p += SZ_EMB;
    _Float16* gi_buf  = (_Float16*)p;   p += gi_bytes;
    _Float16* gi_pe   = (_Float16*)p;   p += SZ_GIPE;   // contiguous after gi_buf
    _Float16* pe_buf  = (_Float16*)p;   p += SZ_PE;
    _Float16* wih_pk  = (_Float16*)p;   p += SZ_WIH;
    _Float16* whh_pk5 = (_Float16*)p;   p += SZ_WHH;
    _Float16* hbf0 = (_Float16*)p;      p += SZ_H;
    _Float16* hbf1 = (_Float16*)p;      p += SZ_H;
    unsigned* flags = (unsigned*)p;     p += SZ_FLAGS;

    hipMemsetAsync(hbf0, 0, SZ_H, stream);
    hipMemsetAsync(flags, 0, SZ_FLAGS, stream);

    setup_kernel<<<16512, 256, 0, stream>>>(
        x, xs_seg, xt_seg, Wih_s, Wih_t, wih_pk, Whh_s, Whh_t, whh_pk5,
        pos_s, ch_s, pos_t, ch_t, pe_buf);

    const size_t giBatchElems = (size_t)16 * 2 * 8 * 16 * 512 * 24;   // elems/batch
    if (big2) {
        // chain 1: steps 0..31 over batches b0,b1
        for (int b = 0; b < 2; ++b) {
            emb_kernel<<<512, 256, 0, stream>>>(xs_seg, xt_seg, W_emb, b_emb,
                                                emb_buf, b * 16);
            gi_gemm_kernel<<<dim3(64, 16, 2), 512, 0, stream>>>(
                emb_buf, pe_buf, wih_pk, gi_buf + (size_t)b * giBatchElems, gi_pe, 0);
        }
        gru_chain_kernel<<<256, 512, 0, stream>>>(
            whh_pk5, gi_buf, bih_s, bhh_s, bih_t, bhh_t,
            hbf0, hbf1, flags, 32, 0);
        // chain 2: steps 32..64 (33 steps; slab 32 = gi_pe = decoder)
        for (int b = 2; b < 4; ++b) {
            emb_kernel<<<512, 256, 0, stream>>>(xs_seg, xt_seg, W_emb, b_emb,
                                                emb_buf, b * 16);
            gi_gemm_kernel<<<dim3(64, 16, 2), 512, 0, stream>>>(
                emb_buf, pe_buf, wih_pk, gi_buf + (size_t)(b - 2) * giBatchElems,
                gi_pe, 0);
        }
        gi_gemm_kernel<<<dim3(64, 1, 2), 512, 0, stream>>>(
            emb_buf, pe_buf, wih_pk, gi_buf, gi_pe, 1);
        gru_chain_kernel<<<256, 512, 0, stream>>>(
            whh_pk5, gi_buf, bih_s, bhh_s, bih_t, bhh_t,
            hbf0, hbf1, flags, 33, 32);
    } else {
        for (int b = 0; b < 4; ++b) {
            emb_kernel<<<512, 256, 0, stream>>>(xs_seg, xt_seg, W_emb, b_emb,
                                                emb_buf, b * 16);
            gi_gemm_kernel<<<dim3(64, 16, 2), 512, 0, stream>>>(
                emb_buf, pe_buf, wih_pk, gi_buf, gi_pe, 0);
            gru_chain_kernel<<<256, 512, 0, stream>>>(
                whh_pk5, gi_buf, bih_s, bhh_s, bih_t, bhh_t,
                hbf0, hbf1, flags, 16, b * 16);
        }
        gi_gemm_kernel<<<dim3(64, 1, 2), 512, 0, stream>>>(
            emb_buf, pe_buf, wih_pk, gi_buf, gi_pe, 1);
        gru_chain_kernel<<<256, 512, 0, stream>>>(
            whh_pk5, gi_pe, bih_s, bhh_s, bih_t, bhh_t,
            hbf0, hbf1, flags, 1, 64);
    }

    head_kernel<<<N_ * SEG_ / 256, 256, 0, stream>>>(
        hbf1, hbf1 + (size_t)N_ * D_, Wps, bps, Wpt, bpt, x, out);
}

// Round 14
// 735.271 us; speedup vs baseline: 1.0712x; 1.0712x over previous
//
#include <hip/hip_runtime.h>
#include <math.h>

#define B_   32
#define L_   1024
#define C_   32
#define D_   512
#define SEG_ 16
#define SX_  64
#define N_   1024   // B*C

typedef _Float16 f16x8 __attribute__((ext_vector_type(8)));
typedef _Float16 f16x4 __attribute__((ext_vector_type(4)));
typedef float    f32x4 __attribute__((ext_vector_type(4)));

__device__ __forceinline__ void stage16(const void* g, void* l) {
    __builtin_amdgcn_global_load_lds((const __attribute__((address_space(1))) void*)g,
                                     (__attribute__((address_space(3))) void*)l, 16, 0, 0);
}
// SC0 LDS-DMA: L2-served h-data path (works because h-tile traffic capacity-
// evicts L1 lines between uses). R8 lesson: NOT valid for tight-loop polling —
// the ONLY correct poll primitive is an AGENT-scope atomic load.
__device__ __forceinline__ void stage16l(const void* g, void* l) {
    __builtin_amdgcn_global_load_lds((const __attribute__((address_space(1))) void*)g,
                                     (__attribute__((address_space(3))) void*)l, 16, 0, 1);
}
__device__ __forceinline__ void store_v4_sc0(void* p, f16x8 v) {
    asm volatile("global_store_dwordx4 %0, %1, off sc0" :: "v"(p), "v"(v) : "memory");
}
__device__ __forceinline__ float fsig(float x) {
    return __builtin_amdgcn_rcpf(1.f + __expf(-x));
}
__device__ __forceinline__ float ftanh(float x) {   // 1 - 2/(e^2x+1), stable both tails
    return 1.f - 2.f * __builtin_amdgcn_rcpf(1.f + __expf(2.f * x));
}

// ---------------------------------------------------------------------------
// fused setup: [0,6144) pack_wih | [6144,12288) pack_whh5 | [12288,16384)
// pack_pe | [16384,16512) prep.
// ---------------------------------------------------------------------------
__global__ __launch_bounds__(256) void setup_kernel(
    const float* __restrict__ x, float* __restrict__ xs_seg, float* __restrict__ xt_seg,
    const float* __restrict__ Wih_s, const float* __restrict__ Wih_t,
    _Float16* __restrict__ wih_pk,
    const float* __restrict__ Whh_s, const float* __restrict__ Whh_t,
    _Float16* __restrict__ whh_pk5,
    const float* __restrict__ pos_s, const float* __restrict__ ch_s,
    const float* __restrict__ pos_t, const float* __restrict__ ch_t,
    _Float16* __restrict__ pe) {
    int bid = blockIdx.x, tid = threadIdx.x;
    if (bid < 6144) {
        // pack Wih -> [gru][kt 16][gc 1536][32 k] f16
        int e = bid * 256 + tid;
        int kk = e & 31;
        int t = e >> 5;
        int gc = t % 1536;
        int t2 = t / 1536;
        int kt = t2 & 15, gru = t2 >> 4;
        int member = gc / 192, r = gc % 192;
        int wn = r / 48, r2 = r % 48;
        int gate = r2 >> 4, jl = r2 & 15;
        int j = member * 64 + wn * 16 + jl;
        int k = kt * 32 + kk;
        const float* W = gru ? Wih_t : Wih_s;
        wih_pk[e] = (_Float16)W[(size_t)(gate * 512 + j) * 512 + k];
    } else if (bid < 12288) {
        // pack Whh pre-swizzled: [gru][m 8][kt 4][chunk 3072][8 f16]
        int e = (bid - 6144) * 256 + tid;
        int fi = e & 7;
        int t = e >> 3;
        int c = t % 3072;
        int t2 = t / 3072;
        int kt = t2 & 3;
        int t3 = t2 >> 2;
        int member = t3 & 7, gru = t3 >> 3;
        int gc = c >> 4, s = c & 15;
        int q = s ^ (gc & 15);
        int k = kt * 128 + q * 8 + fi;
        int wn = gc / 48, r2 = gc % 48;
        int gate = r2 >> 4, jl = r2 & 15;
        int j = member * 64 + wn * 16 + jl;
        const float* W = gru ? Whh_t : Whh_s;
        whh_pk5[e] = (_Float16)W[(size_t)(gate * 512 + j) * 512 + k];
    } else if (bid < 16384) {
        // pe[gru][n][512] f16
        int e = (bid - 12288) * 256 + tid;
        int k = e & 511;
        int n = (e >> 9) & 1023;
        int gru = e >> 19;
        int c = n & 31;
        const float* pos = gru ? pos_t : pos_s;
        const float* ch  = gru ? ch_t  : ch_s;
        float v = (k < 256) ? pos[k] : ch[c * 256 + (k - 256)];
        pe[e] = (_Float16)v;
    } else {
        // prep: moving mean window 25, edge replication
        int b2 = bid - 16384;
        int b = b2 >> 2;
        int t = ((b2 & 3) << 8) + tid;
        const float* xb    = x + (size_t)b * (L_ * C_);
        const float* xrow  = xb + (size_t)t * C_;
        const float* xlast = xb + (size_t)(L_ - 1) * C_;
        float diff[C_];
#pragma unroll
        for (int c = 0; c < C_; ++c) diff[c] = xrow[c] - xlast[c];
        float ps[C_ + 1];
        ps[0] = 0.f;
#pragma unroll
        for (int c = 0; c < C_; ++c) ps[c + 1] = ps[c] + diff[c];
        int s = t >> 4, q = t & 15;
#pragma unroll
        for (int c = 0; c < C_; ++c) {
            int lo = c - 12, hi = c + 12;
            float sum = ps[(hi < 31 ? hi : 31) + 1] - ps[lo > 0 ? lo : 0];
            if (lo < 0)  sum += (float)(-lo)     * diff[0];
            if (hi > 31) sum += (float)(hi - 31) * diff[31];
            float mean = sum * (1.0f / 25.0f);
            size_t idx = ((size_t)s * N_ + (size_t)(b * C_ + c)) * SEG_ + q;
            xt_seg[idx] = mean;
            xs_seg[idx] = diff[c] - mean;
        }
    }
}

// ---------------------------------------------------------------------------
// emb batch: emb_buf[sl][gru][n][512] f16 = relu(xseg @ W_emb^T + b_emb)
// ---------------------------------------------------------------------------
__global__ __launch_bounds__(256) void emb_kernel(
    const float* __restrict__ xs_seg, const float* __restrict__ xt_seg,
    const float* __restrict__ W_emb, const float* __restrict__ b_emb,
    _Float16* __restrict__ emb_buf, int s0) {
    int bid = blockIdx.x;
    int gru = bid >> 8, sl = (bid >> 4) & 15, nch = bid & 15;
    int step = s0 + sl, n0 = nch * 64;
    const float* xseg = gru ? xt_seg : xs_seg;
    __shared__ float xl[64 * 16];
    int tid = threadIdx.x;
    const float* src = xseg + ((size_t)step * N_ + n0) * SEG_;
    for (int i = tid; i < 1024; i += 256) xl[i] = src[i];

    int kg = tid & 127;
    int rh = tid >> 7;
    float w[4][16], bb[4];
#pragma unroll
    for (int i = 0; i < 4; ++i) {
        int k = kg * 4 + i;
        const float4* wr = (const float4*)(W_emb + (size_t)k * 16);
#pragma unroll
        for (int v = 0; v < 4; ++v) {
            float4 tt = wr[v];
            w[i][v * 4 + 0] = tt.x; w[i][v * 4 + 1] = tt.y;
            w[i][v * 4 + 2] = tt.z; w[i][v * 4 + 3] = tt.w;
        }
        bb[i] = b_emb[k];
    }
    __syncthreads();
    _Float16* dst = emb_buf + ((size_t)(sl * 2 + gru) * N_ + n0) * D_ + kg * 4;
    for (int r = 0; r < 32; ++r) {
        int row = rh * 32 + r;
        float a0 = bb[0], a1 = bb[1], a2 = bb[2], a3 = bb[3];
#pragma unroll
        for (int q = 0; q < 16; ++q) {
            float xv = xl[row * 16 + q];
            a0 = fmaf(xv, w[0][q], a0);
            a1 = fmaf(xv, w[1][q], a1);
            a2 = fmaf(xv, w[2][q], a2);
            a3 = fmaf(xv, w[3][q], a3);
        }
        f16x4 v;
        v[0] = (_Float16)(a0 > 0.f ? a0 : 0.f);
        v[1] = (_Float16)(a1 > 0.f ? a1 : 0.f);
        v[2] = (_Float16)(a2 > 0.f ? a2 : 0.f);
        v[3] = (_Float16)(a3 > 0.f ? a3 : 0.f);
        *(f16x4*)(dst + (size_t)row * D_) = v;
    }
}

// ---------------------------------------------------------------------------
// gi GEMM v6 (kept from R13, measured ~15us aggregate gain): v3 tile
// (128M x 192N, BK=32, Mt=x&7) + TRIPLE-BUFFERED staging with counted vmcnt:
// issue batch kt+1 into buf[(kt+1)%3], wait ONLY for batch kt (vmcnt(3) for
// w<4 / vmcnt(2) for w>=4), leaving kt+1 in flight across the barrier. One
// sync/kt; DMA RTT hidden. LDS 60KB, 2 blocks/CU.
// ---------------------------------------------------------------------------
__global__ __launch_bounds__(512, 2) void gi_gemm_kernel(
    const _Float16* __restrict__ emb, const _Float16* __restrict__ pe,
    const _Float16* __restrict__ wih_pack,
    _Float16* __restrict__ gi, _Float16* __restrict__ gi_pe, int mode) {
    __shared__ __align__(16) char smem[61440];  // 3x8K A + 3x12K B; epi: 2x26624
    char* bufA[3] = { smem, smem + 8192, smem + 16384 };
    char* bufB[3] = { smem + 24576, smem + 36864, smem + 49152 };
    int Mt = blockIdx.x & 7, Nt = blockIdx.x >> 3;   // Nt = member 0..7
    int sl = blockIdx.y, gru = blockIdx.z;
    int tid = threadIdx.x, w = tid >> 6, lane = tid & 63;
    int wm = w & 1, wn = w >> 1, ml = lane & 15, qq = lane >> 4;

    const char* Ab = mode ? (const char*)(pe  + (size_t)gru * N_ * D_)
                          : (const char*)(emb + (size_t)(sl * 2 + gru) * N_ * D_);
    const char* Bb = (const char*)wih_pack + (size_t)gru * 16 * 1536 * 64
                     + (size_t)Nt * 192 * 64;

    // A staging: 512 chunks (128 rows x 4 swizzled quads), 1/thread
    int rA = tid >> 2, kqA = (tid & 3) ^ ((rA >> 1) & 3);
    const char* gA = Ab + (size_t)(Mt * 128 + rA) * 1024 + kqA * 16;
    // B staging: 768 chunks (192 gc x 4 quads): call1 all, call2 tid<256
    int g1 = tid >> 2, kq1 = (tid & 3) ^ ((g1 >> 1) & 3);
    int c2 = 512 + tid, g2 = c2 >> 2, kq2 = (c2 & 3) ^ ((g2 >> 1) & 3);

    int offA[4], offB[3];
#pragma unroll
    for (int mf = 0; mf < 4; ++mf) {
        int row = wm * 64 + mf * 16 + ml;
        offA[mf] = (row * 4 + (qq ^ ((row >> 1) & 3))) * 16;
    }
#pragma unroll
    for (int g = 0; g < 3; ++g) {
        int gc = wn * 48 + g * 16 + ml;
        offB[g] = (gc * 4 + (qq ^ ((gc >> 1) & 3))) * 16;
    }

    f32x4 acc[4][3];
#pragma unroll
    for (int mf = 0; mf < 4; ++mf)
#pragma unroll
        for (int g = 0; g < 3; ++g) {
            f32x4 z = {0.f, 0.f, 0.f, 0.f};
            acc[mf][g] = z;
        }

    // prologue: issue batch 0
    {
        stage16(gA, bufA[0] + w * 1024);
        const char* Bkt = Bb;
        stage16(Bkt + g1 * 64 + kq1 * 16, bufB[0] + w * 1024);
        if (w < 4) stage16(Bkt + g2 * 64 + kq2 * 16, bufB[0] + 8192 + w * 1024);
    }

#pragma unroll
    for (int kt = 0; kt < 16; ++kt) {
        if (kt < 15) {
            int kn = kt + 1;
            stage16(gA + kn * 64, bufA[kn % 3] + w * 1024);
            const char* Bkt = Bb + (size_t)kn * (1536 * 64);
            stage16(Bkt + g1 * 64 + kq1 * 16, bufB[kn % 3] + w * 1024);
            if (w < 4) {
                stage16(Bkt + g2 * 64 + kq2 * 16, bufB[kn % 3] + 8192 + w * 1024);
                asm volatile("s_waitcnt vmcnt(3)" ::: "memory");   // batch kt done
            } else {
                asm volatile("s_waitcnt vmcnt(2)" ::: "memory");
            }
        } else {
            asm volatile("s_waitcnt vmcnt(0)" ::: "memory");
        }
        __syncthreads();
        const char* cA = bufA[kt % 3];
        const char* cB = bufB[kt % 3];
        f16x8 a[4];
#pragma unroll
        for (int mf = 0; mf < 4; ++mf) a[mf] = *(const f16x8*)(cA + offA[mf]);
#pragma unroll
        for (int g = 0; g < 3; ++g) {
            f16x8 b = *(const f16x8*)(cB + offB[g]);
#pragma unroll
            for (int mf = 0; mf < 4; ++mf)
                acc[mf][g] = __builtin_amdgcn_mfma_f32_16x16x32_f16(a[mf], b, acc[mf][g], 0, 0, 0);
        }
    }

    // ---- epilogue: LDS transpose into consumer thread-packed layout ----
    __syncthreads();
#pragma unroll
    for (int mf = 0; mf < 4; ++mf) {
        int wm_c = mf >> 1, rt = mf & 1;
        int tid_c = (wn * 2 + wm_c) * 64 + qq * 16 + ml;
        char* base = smem + wm * 26624 + tid_c * 52;
#pragma unroll
        for (int g = 0; g < 3; ++g)
#pragma unroll
            for (int reg = 0; reg < 4; ++reg) {
                int v = rt * 12 + reg * 3 + g;
                *(_Float16*)(base + v * 2) = (_Float16)acc[mf][g][reg];
            }
    }
    __syncthreads();
    _Float16* ob = mode ? gi_pe + (size_t)gru * 8 * 16 * 512 * 24
                        : gi    + (size_t)(sl * 2 + gru) * 8 * 16 * 512 * 24;
    char* obB = (char*)ob;
#pragma unroll
    for (int s = 0; s < 6; ++s) {
        int o = tid * 16 + s * 8192;           // 0..49135 logical (2 slabs x 24576)
        int mc = o / 24576;
        int o2 = o - mc * 24576;
        int tc = o2 / 48;
        int r  = o2 - tc * 48;                 // 0 / 16 / 32 (never straddles)
        const char* src = smem + mc * 26624 + tc * 52 + r;
        int4 val;
        val.x = *(const int*)(src);
        val.y = *(const int*)(src + 4);
        val.z = *(const int*)(src + 8);
        val.w = *(const int*)(src + 12);
        *(int4*)(obB + (size_t)(Nt * 16 + Mt * 2 + mc) * 24576 + o2) = val;
    }
}

// ---------------------------------------------------------------------------
// Persistent chain scan — EXACT R12 body (proven 5.47us/step): 256 blocks x
// 512 thr, 32 chains x 8 members, Whh register-resident, XCD co-location
// (member=bid>>5), h exchange in local L2 (sc0 stores + sc0 load_lds), gi
// prefetched a full step early, separate sEx (115KB LDS). Flag barrier:
// tid0 AGENT-atomic store after block drain + 8-lane read-only poll on 8
// padded lines. R13 lesson: poll fan-in WIDTH is the cost driver — the
// 64-wide per-wave variant cost +25us/dispatch. Keep the reader side narrow.
// ---------------------------------------------------------------------------
__global__ __launch_bounds__(512) void gru_chain_kernel(
    const _Float16* __restrict__ whh_pk5,  // [gru][m8][kt4][3072][8]
    const _Float16* __restrict__ gi_base,  // [it][gru][m8][Mt16][512][24]
    const float* __restrict__ bih_s, const float* __restrict__ bhh_s,
    const float* __restrict__ bih_t, const float* __restrict__ bhh_t,
    _Float16* __restrict__ hbf0, _Float16* __restrict__ hbf1,
    unsigned* __restrict__ flags, int nsteps, int sbase) {
    __shared__ __align__(16) char sA[65536];   // h tile [row 64][64 chunks x 16B], XOR-16 swizzle
    __shared__ __align__(16) char sEx[49152];  // partial-sum exchange: 12 planes x [256][16B]
    int bid = blockIdx.x;
    int member = bid >> 5, chain = bid & 31;   // co-location: bid%8 == chain%8 -> same XCD
    int Mt = chain & 15, gru = chain >> 4;
    int tid = threadIdx.x, w = tid >> 6, lane = tid & 63;
    int ml = lane & 15, qq = lane >> 4;
    int km = w & 1, wn = w >> 1;   // km: K-half, wn: j sub-block

    const char* h0 = (const char*)hbf0 + ((size_t)gru * N_ + Mt * 64) * 1024;
    const char* h1 = (const char*)hbf1 + ((size_t)gru * N_ + Mt * 64) * 1024;

    // Whh fragments persistent in registers: bfr[g][ks] (96 VGPRs)
    f16x8 bfr[3][8];
    {
        const _Float16* Wb = whh_pk5 + (size_t)(gru * 8 + member) * 4 * 24576;
#pragma unroll
        for (int g = 0; g < 3; ++g) {
            int gc = wn * 48 + g * 16 + ml;
#pragma unroll
            for (int ks = 0; ks < 8; ++ks) {
                int kt = km * 2 + (ks >> 2);
                int q8 = ((ks & 3) * 4 + qq) ^ (gc & 15);
                bfr[g][ks] = *(const f16x8*)(Wb + (size_t)kt * 24576
                                             + (size_t)(gc * 16 + q8) * 8);
            }
        }
    }

    int cS0 = (lane & 48) | ((lane & 15) ^ (w & 15));
    int cS1 = (lane & 48) | ((lane & 15) ^ ((w + 8) & 15));

    int offR[4], cp[8];
#pragma unroll
    for (int rt = 0; rt < 4; ++rt) offR[rt] = (rt * 16 + ml) * 1024;
#pragma unroll
    for (int ks = 0; ks < 8; ++ks) {
        int c = km * 32 + ks * 4 + qq;
        cp[ks] = ((c & 48) | ((c & 15) ^ ml)) * 16;
    }

    const float* bi = gru ? bih_t : bih_s;
    const float* bh = gru ? bhh_t : bhh_s;
    int j = member * 64 + wn * 16 + ml;
    float bir = bi[j], biz = bi[D_ + j], bin = bi[2 * D_ + j];
    float bhr = bh[j], bhz = bh[D_ + j], bhn = bh[2 * D_ + j];
    float hp[2][4];
#pragma unroll
    for (int rtL = 0; rtL < 2; ++rtL)
#pragma unroll
        for (int reg = 0; reg < 4; ++reg) {
            int row = Mt * 64 + km * 32 + rtL * 16 + qq * 4 + reg;
            hp[rtL][reg] = (float)hbf0[((size_t)gru * N_ + row) * D_ + j];
        }

    unsigned* fbase = flags + chain * 256;     // 1KB per chain; member word @ +member*32
    const _Float16* giTid0 = gi_base
        + (((size_t)gru * 8 + member) * 16 + Mt) * 512 * 24 + (size_t)tid * 24;
    size_t giStep = (size_t)2 * 8 * 16 * 512 * 24;

    int dir0 = sbase & 1;
    f16x8 gv0, gv1, gv2;
    {
        const _Float16* gp = giTid0;
        gv0 = *(const f16x8*)(gp);
        gv1 = *(const f16x8*)(gp + 8);
        gv2 = *(const f16x8*)(gp + 16);
        const char* hin = dir0 ? h1 : h0;
#pragma unroll
        for (int r = 0; r < 8; ++r) {
            int row = r * 8 + w;
            stage16l(hin + (size_t)row * 1024 + (size_t)((r & 1) ? cS1 : cS0) * 16,
                     sA + row * 1024);
        }
    }

    for (int it = 0; it < nsteps; ++it) {
        int gstep = sbase + it;
        _Float16* hout = (gstep & 1) ? hbf0 : hbf1;

        f32x4 acc[4][3];
#pragma unroll
        for (int rt = 0; rt < 4; ++rt)
#pragma unroll
            for (int g = 0; g < 3; ++g) {
                f32x4 z = {0.f, 0.f, 0.f, 0.f};
                acc[rt][g] = z;
            }

        asm volatile("s_waitcnt vmcnt(0)" ::: "memory");   // A (+prev gi) arrival
        __syncthreads();

        // issue next-step gi (ping-pong regs); the publish vmcnt(0) is its wait
        int itn = (it + 1 < nsteps) ? it + 1 : it;
        const _Float16* gpn = giTid0 + (size_t)itn * giStep;
        f16x8 ngv0 = *(const f16x8*)(gpn);
        f16x8 ngv1 = *(const f16x8*)(gpn + 8);
        f16x8 ngv2 = *(const f16x8*)(gpn + 16);
        __builtin_amdgcn_sched_barrier(0);

#pragma unroll
        for (int ks = 0; ks < 8; ++ks) {
            f16x8 a0 = *(const f16x8*)(sA + offR[0] + cp[ks]);
            f16x8 a1 = *(const f16x8*)(sA + offR[1] + cp[ks]);
            f16x8 a2 = *(const f16x8*)(sA + offR[2] + cp[ks]);
            f16x8 a3 = *(const f16x8*)(sA + offR[3] + cp[ks]);
#pragma unroll
            for (int g = 0; g < 3; ++g) {
                acc[0][g] = __builtin_amdgcn_mfma_f32_16x16x32_f16(a0, bfr[g][ks], acc[0][g], 0, 0, 0);
                acc[1][g] = __builtin_amdgcn_mfma_f32_16x16x32_f16(a1, bfr[g][ks], acc[1][g], 0, 0, 0);
                acc[2][g] = __builtin_amdgcn_mfma_f32_16x16x32_f16(a2, bfr[g][ks], acc[2][g], 0, 0, 0);
                acc[3][g] = __builtin_amdgcn_mfma_f32_16x16x32_f16(a3, bfr[g][ks], acc[3][g], 0, 0, 0);
            }
        }

        // K-half reduce: publish the row-half this side does NOT finish.
        char* exw = sEx + (size_t)(wn * 64 + lane) * 16;
        if (km == 0) {
#pragma unroll
            for (int g = 0; g < 3; ++g) {
                *(f32x4*)(exw + (size_t)(6 + g) * 4096) = acc[2][g];
                *(f32x4*)(exw + (size_t)(9 + g) * 4096) = acc[3][g];
            }
        } else {
#pragma unroll
            for (int g = 0; g < 3; ++g) {
                *(f32x4*)(exw + (size_t)(0 + g) * 4096) = acc[0][g];
                *(f32x4*)(exw + (size_t)(3 + g) * 4096) = acc[1][g];
            }
        }
        __syncthreads();
        f32x4 s0[3], s1[3];
        if (km == 0) {
#pragma unroll
            for (int g = 0; g < 3; ++g) {
                s0[g] = acc[0][g] + *(const f32x4*)(exw + (size_t)(0 + g) * 4096);
                s1[g] = acc[1][g] + *(const f32x4*)(exw + (size_t)(3 + g) * 4096);
            }
        } else {
#pragma unroll
            for (int g = 0; g < 3; ++g) {
                s0[g] = acc[2][g] + *(const f32x4*)(exw + (size_t)(6 + g) * 4096);
                s1[g] = acc[3][g] + *(const f32x4*)(exw + (size_t)(9 + g) * 4096);
            }
        }

        // epilogue: compute 8 h/thread into LDS h-tile (aliases sA; A reads
        // all completed before the exchange barrier)
        char* sH = sA;                 // [64 rows][stride 144]
        int colb = (wn * 16 + ml) * 2;
#pragma unroll
        for (int reg = 0; reg < 4; ++reg) {     // rtL = 0
            int v0 = reg * 3;
            float gr = (float)((v0 + 0) < 8 ? gv0[(v0 + 0) & 7]
                      : ((v0 + 0) < 16 ? gv1[(v0 + 0) & 7] : gv2[(v0 + 0) & 7]));
            float gz = (float)((v0 + 1) < 8 ? gv0[(v0 + 1) & 7]
                      : ((v0 + 1) < 16 ? gv1[(v0 + 1) & 7] : gv2[(v0 + 1) & 7]));
            float gn = (float)((v0 + 2) < 8 ? gv0[(v0 + 2) & 7]
                      : ((v0 + 2) < 16 ? gv1[(v0 + 2) & 7] : gv2[(v0 + 2) & 7]));
            float r = fsig(s0[0][reg] + gr + bir + bhr);
            float z = fsig(s0[1][reg] + gz + biz + bhz);
            float nn = ftanh(gn + bin + r * (s0[2][reg] + bhn));
            float hv = (1.f - z) * nn + z * hp[0][reg];
            hp[0][reg] = hv;
            int rl = km * 32 + qq * 4 + reg;
            *(_Float16*)(sH + rl * 144 + colb) = (_Float16)hv;
        }
#pragma unroll
        for (int reg = 0; reg < 4; ++reg) {     // rtL = 1
            int v0 = 12 + reg * 3;
            float gr = (float)((v0 + 0) < 8 ? gv0[(v0 + 0) & 7]
                      : ((v0 + 0) < 16 ? gv1[(v0 + 0) & 7] : gv2[(v0 + 0) & 7]));
            float gz = (float)((v0 + 1) < 8 ? gv0[(v0 + 1) & 7]
                      : ((v0 + 1) < 16 ? gv1[(v0 + 1) & 7] : gv2[(v0 + 1) & 7]));
            float gn = (float)((v0 + 2) < 8 ? gv0[(v0 + 2) & 7]
                      : ((v0 + 2) < 16 ? gv1[(v0 + 2) & 7] : gv2[(v0 + 2) & 7]));
            float r = fsig(s1[0][reg] + gr + bir + bhr);
            float z = fsig(s1[1][reg] + gz + biz + bhz);
            float nn = ftanh(gn + bin + r * (s1[2][reg] + bhn));
            float hv = (1.f - z) * nn + z * hp[1][reg];
            hp[1][reg] = hv;
            int rl = km * 32 + 16 + qq * 4 + reg;
            *(_Float16*)(sH + rl * 144 + colb) = (_Float16)hv;
        }
        __syncthreads();
        // coalesced h store: 16B/thread
        {
            int srow = tid >> 3, spart = tid & 7;
            f16x8 hv8 = *(const f16x8*)(sH + srow * 144 + spart * 16);
            _Float16* gdst = hout + ((size_t)gru * N_ + Mt * 64 + srow) * D_
                             + member * 64 + spart * 8;
            store_v4_sc0(gdst, hv8);
        }

        asm volatile("s_waitcnt vmcnt(0)" ::: "memory");   // h stores + ngv drained
        __syncthreads();                                   // block-wide drain
        if (tid == 0)
            __hip_atomic_store(fbase + member * 32, (unsigned)(gstep + 1),
                               __ATOMIC_RELAXED, __HIP_MEMORY_SCOPE_AGENT);

        if (it < nsteps - 1) {
            if (w == 0) {
                const unsigned* fp = fbase + (lane & 7) * 32;
                unsigned tgt = (unsigned)(gstep + 1);
                int guard = 0;
                while (true) {
                    unsigned v = __hip_atomic_load(fp, __ATOMIC_RELAXED,
                                                   __HIP_MEMORY_SCOPE_AGENT);
                    if (__all(v >= tgt)) break;
                    __builtin_amdgcn_s_sleep(1);
                    if (++guard > (1 << 20)) break;   // bail: fail, don't hang
                }
            }
            __syncthreads();
            const char* hinN = ((gstep + 1) & 1) ? h1 : h0;
#pragma unroll
            for (int r = 0; r < 8; ++r) {
                int row = r * 8 + w;
                stage16l(hinN + (size_t)row * 1024 + (size_t)((r & 1) ? cS1 : cS0) * 16,
                         sA + row * 1024);
            }
        }
        gv0 = ngv0; gv1 = ngv1; gv2 = ngv2;
    }
}

// ---------------------------------------------------------------------------
__global__ __launch_bounds__(256) void head_kernel(
    const _Float16* __restrict__ hs2, const _Float16* __restrict__ ht2,
    const float* __restrict__ Wps, const float* __restrict__ bps,
    const float* __restrict__ Wpt, const float* __restrict__ bpt,
    const float* __restrict__ x, float* __restrict__ out) {
    int g = blockIdx.x * 256 + threadIdx.x;
    int n = g >> 4, p = g & 15;
    int b = n >> 5, c = n & 31;
    const _Float16* hs = hs2 + (size_t)n * D_;
    const _Float16* ht = ht2 + (size_t)n * D_;
    const float* ws = Wps + (size_t)p * D_;
    const float* wt = Wpt + (size_t)p * D_;
    float acc = bps[p] + bpt[p];
    for (int k = 0; k < D_; ++k)
        acc += (float)hs[k] * ws[k] + (float)ht[k] * wt[k];
    float last = x[((size_t)b * L_ + (L_ - 1)) * C_ + c];
    out[((size_t)b * SEG_ + p) * C_ + c] = acc + last;
}

// ---------------------------------------------------------------------------
extern "C" void kernel_launch(void* const* d_in, const int* in_sizes, int n_in,
                              void* d_out, int out_size, void* d_ws, size_t ws_size,
                              hipStream_t stream) {
    const float* x     = (const float*)d_in[0];
    const float* W_emb = (const float*)d_in[1];
    const float* b_emb = (const float*)d_in[2];
    const float* Wih_s = (const float*)d_in[3];
    const float* Whh_s = (const float*)d_in[4];
    const float* bih_s = (const float*)d_in[5];
    const float* bhh_s = (const float*)d_in[6];
    const float* Wih_t = (const float*)d_in[7];
    const float* Whh_t = (const float*)d_in[8];
    const float* bih_t = (const float*)d_in[9];
    const float* bhh_t = (const float*)d_in[10];
    const float* pos_s = (const float*)d_in[11];
    const float* ch_s  = (const float*)d_in[12];
    const float* pos_t = (const float*)d_in[13];
    const float* ch_t  = (const float*)d_in[14];
    const float* Wps   = (const float*)d_in[15];
    const float* bps   = (const float*)d_in[16];
    const float* Wpt   = (const float*)d_in[17];
    const float* bpt   = (const float*)d_in[18];
    float* out = (float*)d_out;

    const size_t SZ_XS    = (size_t)SX_ * N_ * SEG_ * 4;            // 4 MB
    const size_t SZ_EMB   = (size_t)16 * 2 * N_ * D_ * 2;           // 32 MB
    const size_t SZ_GIB   = (size_t)16 * 2 * 8 * 16 * 512 * 24 * 2; // ~100.7 MB / batch
    const size_t SZ_GIPE  = (size_t)2 * 8 * 16 * 512 * 24 * 2;
    const size_t SZ_PE    = (size_t)2 * N_ * D_ * 2;
    const size_t SZ_WIH   = (size_t)2 * 16 * 1536 * 32 * 2;
    const size_t SZ_WHH   = (size_t)2 * 8 * 4 * 3072 * 8 * 2;
    const size_t SZ_H     = (size_t)2 * N_ * D_ * 2;
    const size_t SZ_FLAGS = 32 * 256 * 4;                           // 32 KB
    const size_t fixed = 2 * SZ_XS + SZ_EMB + SZ_GIPE + SZ_PE + SZ_WIH + SZ_WHH
                         + 2 * SZ_H + SZ_FLAGS;
    // 2-batch tier (proven R12): two long chains; gi_pe sits contiguously
    // after gi_buf, so slab 32 of gi_buf IS gi_pe -> decoder folds into
    // chain 2 (33 steps).
    const bool big2 = ws_size >= fixed + 2 * SZ_GIB;
    const size_t gi_bytes = big2 ? 2 * SZ_GIB : SZ_GIB;

    char* p = (char*)d_ws;
    float* xs_seg = (float*)p;          p += SZ_XS;
    float* xt_seg = (float*)p;          p += SZ_XS;
    _Float16* emb_buf = (_Float16*)p;   p += SZ_EMB;
    _Float16* gi_buf  = (_Float16*)p;   p += gi_bytes;
    _Float16* gi_pe   = (_Float16*)p;   p += SZ_GIPE;   // contiguous after gi_buf
    _Float16* pe_buf  = (_Float16*)p;   p += SZ_PE;
    _Float16* wih_pk  = (_Float16*)p;   p += SZ_WIH;
    _Float16* whh_pk5 = (_Float16*)p;   p += SZ_WHH;
    _Float16* hbf0 = (_Float16*)p;      p += SZ_H;
    _Float16* hbf1 = (_Float16*)p;      p += SZ_H;
    unsigned* flags = (unsigned*)p;     p += SZ_FLAGS;

    hipMemsetAsync(hbf0, 0, SZ_H, stream);
    hipMemsetAsync(flags, 0, SZ_FLAGS, stream);

    setup_kernel<<<16512, 256, 0, stream>>>(
        x, xs_seg, xt_seg, Wih_s, Wih_t, wih_pk, Whh_s, Whh_t, whh_pk5,
        pos_s, ch_s, pos_t, ch_t, pe_buf);

    const size_t giBatchElems = (size_t)16 * 2 * 8 * 16 * 512 * 24;   // elems/batch
    if (big2) {
        // chain 1: steps 0..31 over batches b0,b1
        for (int b = 0; b < 2; ++b) {
            emb_kernel<<<512, 256, 0, stream>>>(xs_seg, xt_seg, W_emb, b_emb,
                                                emb_buf, b * 16);
            gi_gemm_kernel<<<dim3(64, 16, 2), 512, 0, stream>>>(
                emb_buf, pe_buf, wih_pk, gi_buf + (size_t)b * giBatchElems, gi_pe, 0);
        }
        gru_chain_kernel<<<256, 512, 0, stream>>>(
            whh_pk5, gi_buf, bih_s, bhh_s, bih_t, bhh_t,
            hbf0, hbf1, flags, 32, 0);
        // chain 2: steps 32..64 (33 steps; slab 32 = gi_pe = decoder)
        for (int b = 2; b < 4; ++b) {
            emb_kernel<<<512, 256, 0, stream>>>(xs_seg, xt_seg, W_emb, b_emb,
                                                emb_buf, b * 16);
            gi_gemm_kernel<<<dim3(64, 16, 2), 512, 0, stream>>>(
                emb_buf, pe_buf, wih_pk, gi_buf + (size_t)(b - 2) * giBatchElems,
                gi_pe, 0);
        }
        gi_gemm_kernel<<<dim3(64, 1, 2), 512, 0, stream>>>(
            emb_buf, pe_buf, wih_pk, gi_buf, gi_pe, 1);
        gru_chain_kernel<<<256, 512, 0, stream>>>(
            whh_pk5, gi_buf, bih_s, bhh_s, bih_t, bhh_t,
            hbf0, hbf1, flags, 33, 32);
    } else {
        for (int b = 0; b < 4; ++b) {
            emb_kernel<<<512, 256, 0, stream>>>(xs_seg, xt_seg, W_emb, b_emb,
                                                emb_buf, b * 16);
            gi_gemm_kernel<<<dim3(64, 16, 2), 512, 0, stream>>>(
                emb_buf, pe_buf, wih_pk, gi_buf, gi_pe, 0);
            gru_chain_kernel<<<256, 512, 0, stream>>>(
                whh_pk5, gi_buf, bih_s, bhh_s, bih_t, bhh_t,
                hbf0, hbf1, flags, 16, b * 16);
        }
        gi_gemm_kernel<<<dim3(64, 1, 2), 512, 0, stream>>>(
            emb_buf, pe_buf, wih_pk, gi_buf, gi_pe, 1);
        gru_chain_kernel<<<256, 512, 0, stream>>>(
            whh_pk5, gi_pe, bih_s, bhh_s, bih_t, bhh_t,
            hbf0, hbf1, flags, 1, 64);
    }

    head_kernel<<<N_ * SEG_ / 256, 256, 0, stream>>>(
        hbf1, hbf1 + (size_t)N_ * D_, Wps, bps, Wpt, bpt, x, out);
}